// Round 5
// baseline (133.722 us; speedup 1.0000x reference)
//
#include <hip/hip_runtime.h>
#include <hip/hip_bf16.h>

// StyleGAN3 filtered_lrelu, fused. R5: 2-row C stage, col-quad b128 A stage,
// XOR-swizzled bf16 ZS to cut LDS bank conflicts.
//
// Math (identical to verified R1..R4):
//   fk[t] = f[11-t]
//   up (per axis, gain 2): out idx i: base=i>>1, tap0=1-(i&1):
//       v[i] = 2 * sum_{s<6} fk[2s+tap0] * src[base+s]
//   leaky relu slope 0.01 between up and down
//   down (per axis): out[o] = sum_{t<12} fk[t] * z[2o+t]
//
// Tile 32x32 out / block, 256 threads. LDS (dwords):
//   XS [42][44] f32 @0      (halo, dead after A)
//   VS [74][44] f32 @1848   (vert-up, dead after B)
//   WS [32][84] f32 @1848   (vert-down, overlays VS)
//   ZS [74][40] bf16x2 @5104 (up+lrelu; z cols >=74 garbage-ok, D reads <=73)
//     ZS dword-col for oct o<8 is (4o)^((row&7)<<2); octs 8,9 unswizzled.
// total 8064 dw = 31.5 KB -> 5 blocks/CU.

#define TAPS 12
#define XS 0
#define XSS 44
#define VS 1848
#define VSS 44
#define WS 1848
#define WSS 84
#define ZS 5104
#define ZSS 40
#define LDS_DW 8064

__device__ __forceinline__ float bl(unsigned u){ return __uint_as_float(u << 16); }
__device__ __forceinline__ float bh(unsigned u){ return __uint_as_float(u & 0xffff0000u); }
__device__ __forceinline__ unsigned pk_bf2(float lo, float hi){
    __hip_bfloat16 a = __float2bfloat16(lo), b = __float2bfloat16(hi);
    unsigned short ua, ub;
    __builtin_memcpy(&ua, &a, 2); __builtin_memcpy(&ub, &b, 2);
    return (unsigned)ua | ((unsigned)ub << 16);
}

__global__ __launch_bounds__(256) void flrelu_fused(
    const float* __restrict__ x, const float* __restrict__ f, float* __restrict__ out)
{
    __shared__ float smem[LDS_DW];
    unsigned* smemu = reinterpret_cast<unsigned*>(smem);

    const int tid = threadIdx.x;
    const int nc  = blockIdx.y;
    const int ho0 = (blockIdx.x >> 2) * 32;
    const int wo0 = (blockIdx.x & 3) * 32;

    float fk[TAPS];
#pragma unroll
    for (int t = 0; t < TAPS; ++t) fk[t] = f[TAPS - 1 - t];

    const float* xin = x + (size_t)nc * (128 * 128);

    // ---- halo load: 42x42 fp32 ----
#pragma unroll
    for (int k = 0; k < 7; ++k) {
        int e = tid + 256 * k;
        if (e < 42 * 42) {
            int r = e / 42, c = e - r * 42;
            int gr = ho0 - 5 + r, gc = wo0 - 5 + c;
            float v = 0.f;
            if ((unsigned)gr < 128u && (unsigned)gc < 128u) v = xin[gr * 128 + gc];
            smem[XS + r * XSS + c] = v;
        }
    }
    __syncthreads();

    // ---- A: vertical up (fp32 -> VS). task = (col-quad cq<11, 2-row chunk mc<19) ----
    // reads xs rows 2mc..2mc+6 (b128), writes v rows 4mc..4mc+3 cols 4cq..4cq+3.
    if (tid < 209) {
        int cq = tid % 11, mc = tid / 11;
        const float* xb = smem + XS + 4 * cq;
        float4 xv[7];
#pragma unroll
        for (int s = 0; s < 7; ++s) {
            int r = 2 * mc + s; r = r < 42 ? r : 41;   // clamped row feeds only skipped m
            xv[s] = *(const float4*)(xb + r * XSS);
        }
#pragma unroll
        for (int k2 = 0; k2 < 2; ++k2) {
            int m = 2 * mc + k2;
            if (m < 37) {
                float ex=0.f,ey=0.f,ez=0.f,ew=0.f, ox=0.f,oy=0.f,oz=0.f,ow=0.f;
#pragma unroll
                for (int s = 0; s < 6; ++s) {
                    float4 xr = xv[k2 + s];
                    float we = fk[2*s+1], wo2 = fk[2*s];
                    ex += we*xr.x; ey += we*xr.y; ez += we*xr.z; ew += we*xr.w;
                    ox += wo2*xr.x; oy += wo2*xr.y; oz += wo2*xr.z; ow += wo2*xr.w;
                }
                float* vp0 = smem + VS + (2*m) * VSS + 4*cq;
                *(float4*)vp0        = make_float4(2.f*ex, 2.f*ey, 2.f*ez, 2.f*ew);
                *(float4*)(vp0+VSS)  = make_float4(2.f*ox, 2.f*oy, 2.f*oz, 2.f*ow);
            }
        }
    }
    __syncthreads();

    // ---- B: horizontal up + lrelu (VS -> ZS bf16, swizzled). task = (row i<74, chunk q<5) ----
#pragma unroll
    for (int it = 0; it < 2; ++it) {
        int task = tid + 256 * it;
        if (task < 370) {
            int q = task % 5, i = task / 5;
            const float* vp = smem + VS + i * VSS + 8 * q;
            float4 a  = *(const float4*)(vp);
            float4 b  = *(const float4*)(vp + 4);
            float4 cc = *(const float4*)(vp + 8);
            float c12 = vp[12];
            float c[13] = { a.x,a.y,a.z,a.w, b.x,b.y,b.z,b.w, cc.x,cc.y,cc.z,cc.w, c12 };
            unsigned pkz[8];
#pragma unroll
            for (int h = 0; h < 8; ++h) {            // j = 16q+2h (lo), 16q+2h+1 (hi)
                float ze = 0.f, zo = 0.f;
#pragma unroll
                for (int s = 0; s < 6; ++s) {
                    ze += fk[2*s+1] * c[h+s];
                    zo += fk[2*s]   * c[h+s];
                }
                ze *= 2.f; zo *= 2.f;
                ze = ze >= 0.f ? ze : 0.01f * ze;
                zo = zo >= 0.f ? zo : 0.01f * zo;
                pkz[h] = pk_bf2(ze, zo);
            }
            int sw = (i & 7) << 2;
            int c0 = 8 * q,  c1 = 8 * q + 4;
            if (q < 4) { c0 ^= sw; c1 ^= sw; }
            unsigned* zrow = smemu + ZS + i * ZSS;
            *(uint4*)(zrow + c0) = make_uint4(pkz[0], pkz[1], pkz[2], pkz[3]);
            *(uint4*)(zrow + c1) = make_uint4(pkz[4], pkz[5], pkz[6], pkz[7]);
        }
    }
    __syncthreads();

    // ---- C: vertical down (ZS -> WS fp32). task = (col-oct p8<10, row-pair hc<16) ----
    // outputs ws rows 2hc, 2hc+1; reads z rows 4hc..4hc+13.
    if (tid < 160) {
        int p8 = tid % 10, hc = tid / 10;
        int r0 = 4 * hc;
        float a0=0.f,a1=0.f,a2=0.f,a3=0.f,a4=0.f,a5=0.f,a6=0.f,a7=0.f;
        float b0=0.f,b1=0.f,b2=0.f,b3=0.f,b4=0.f,b5=0.f,b6=0.f,b7=0.f;
#pragma unroll
        for (int u = 0; u < 14; ++u) {
            int row = r0 + u;
            int colr = 4 * p8;
            if (p8 < 8) colr ^= ((row & 7) << 2);
            uint4 zr = *(const uint4*)(smemu + ZS + row * ZSS + colr);
            float z0 = bl(zr.x), z1 = bh(zr.x), z2 = bl(zr.y), z3 = bh(zr.y);
            float z4 = bl(zr.z), z5 = bh(zr.z), z6 = bl(zr.w), z7 = bh(zr.w);
            if (u < 12) {
                float w = fk[u];
                a0 += w*z0; a1 += w*z1; a2 += w*z2; a3 += w*z3;
                a4 += w*z4; a5 += w*z5; a6 += w*z6; a7 += w*z7;
            }
            if (u >= 2) {
                float w = fk[u - 2];
                b0 += w*z0; b1 += w*z1; b2 += w*z2; b3 += w*z3;
                b4 += w*z4; b5 += w*z5; b6 += w*z6; b7 += w*z7;
            }
        }
        float* wp = smem + WS + (2 * hc) * WSS + 8 * p8;
        *(float4*)(wp)           = make_float4(a0, a1, a2, a3);
        *(float4*)(wp + 4)       = make_float4(a4, a5, a6, a7);
        *(float4*)(wp + WSS)     = make_float4(b0, b1, b2, b3);
        *(float4*)(wp + WSS + 4) = make_float4(b4, b5, b6, b7);
    }
    __syncthreads();

    // ---- D: horizontal down (WS -> global). task = (ho = tid>>3, col-quad w4 = tid&7) ----
    {
        int ho = tid >> 3, w4 = tid & 7;
        const float* wp = smem + WS + ho * WSS + 8 * w4;
        float4 r0 = *(const float4*)(wp);
        float4 r1 = *(const float4*)(wp + 4);
        float4 r2 = *(const float4*)(wp + 8);
        float4 r3 = *(const float4*)(wp + 12);
        float2 r4 = *(const float2*)(wp + 16);
        float w[18] = { r0.x,r0.y,r0.z,r0.w, r1.x,r1.y,r1.z,r1.w,
                        r2.x,r2.y,r2.z,r2.w, r3.x,r3.y,r3.z,r3.w, r4.x,r4.y };
        float o[4];
#pragma unroll
        for (int v = 0; v < 4; ++v) {
            float acc = 0.f;
#pragma unroll
            for (int t = 0; t < TAPS; ++t) acc += fk[t] * w[2 * v + t];
            o[v] = acc;
        }
        *(float4*)(out + ((size_t)nc * 128 + (ho0 + ho)) * 128 + wo0 + 4 * w4)
            = make_float4(o[0], o[1], o[2], o[3]);
    }
}

extern "C" void kernel_launch(void* const* d_in, const int* in_sizes, int n_in,
                              void* d_out, int out_size, void* d_ws, size_t ws_size,
                              hipStream_t stream) {
    const float* x = (const float*)d_in[0];
    const float* f = (const float*)d_in[1];
    float* out = (float*)d_out;
    dim3 grid(16, 1024);
    flrelu_fused<<<grid, 256, 0, stream>>>(x, f, out);
}

// Round 6
// 105.543 us; speedup vs baseline: 1.2670x; 1.2670x over previous
//
#include <hip/hip_runtime.h>

// StyleGAN3 filtered_lrelu, fused. R6 = R4 skeleton + fp16 ZS with packed
// v_pk_fma_f16 in C (kills bf16 unpack VALU ops), gain folded into taps,
// 2-row sliding C stage (fewer LDS reads). No ZS swizzle (R5: no effect).
//
// Math (identical to verified R1..R5):
//   fk[t] = f[11-t];  fkU[t] = 2*fk[t]  (per-pass up-gain folded in)
//   up (per axis): out idx i: base=i>>1, tap0=1-(i&1):
//       v[i] = sum_{s<6} fkU[2s+tap0] * src[base+s]
//   leaky relu slope 0.01 between up and down
//   down (per axis): out[o] = sum_{t<12} fk[t] * z[2o+t]
//
// Tile 32x32 out / block, 256 threads. LDS (dwords):
//   XS [42][44] f32 @0      (halo, dead after A)
//   VS [74][44] f32 @1848   (vert-up, dead after B)
//   WS [32][84] f32 @1848   (vert-down, overlays VS)
//   ZS [74][40] f16x2 @5104 (up+lrelu; cols >=74 garbage-ok, D reads <=73)
// total 8064 dw = 31.5 KB.

#define TAPS 12
#define XS 0
#define XSS 44
#define VS 1848
#define VSS 44
#define WS 1848
#define WSS 84
#define ZS 5104
#define ZSS 40
#define LDS_DW 8064

typedef _Float16 half_t;
typedef half_t h2 __attribute__((ext_vector_type(2)));

__device__ __forceinline__ h2 u2h(unsigned u){ h2 r; __builtin_memcpy(&r, &u, 4); return r; }
__device__ __forceinline__ unsigned h2u(h2 h){ unsigned u; __builtin_memcpy(&u, &h, 4); return u; }

__global__ __launch_bounds__(256) void flrelu_fused(
    const float* __restrict__ x, const float* __restrict__ f, float* __restrict__ out)
{
    __shared__ float smem[LDS_DW];
    unsigned* smemu = reinterpret_cast<unsigned*>(smem);

    const int tid = threadIdx.x;
    const int nc  = blockIdx.y;
    const int ho0 = (blockIdx.x >> 2) * 32;
    const int wo0 = (blockIdx.x & 3) * 32;

    // fkU[t] = 2 * f[11-t]  (up-stage taps with gain folded)
    float fkU[TAPS];
#pragma unroll
    for (int t = 0; t < TAPS; ++t) fkU[t] = 2.0f * f[TAPS - 1 - t];

    const float* xin = x + (size_t)nc * (128 * 128);

    // ---- halo load: 42x42 fp32 ----
#pragma unroll
    for (int k = 0; k < 7; ++k) {
        int e = tid + 256 * k;
        if (e < 42 * 42) {
            int r = e / 42, c = e - r * 42;
            int gr = ho0 - 5 + r, gc = wo0 - 5 + c;
            float v = 0.f;
            if ((unsigned)gr < 128u && (unsigned)gc < 128u) v = xin[gr * 128 + gc];
            smem[XS + r * XSS + c] = v;
        }
    }
    __syncthreads();

    // ---- A: vertical up (fp32 -> VS). task = (col-pair cp<21, m-chunk mc<10) ----
    if (tid < 210) {
        int cp = tid % 21, mc = tid / 21;
        int m0 = mc * 4;
        float2 v[9];
#pragma unroll
        for (int s = 0; s < 9; ++s) {
            int r = m0 + s; r = r < 42 ? r : 41;      // clamped rows feed only skipped m
            v[s] = *(const float2*)(smem + XS + r * XSS + 2 * cp);
        }
#pragma unroll
        for (int k = 0; k < 4; ++k) {
            int m = m0 + k;
            if (m < 37) {
                float ex = 0.f, ey = 0.f, ox = 0.f, oy = 0.f;
#pragma unroll
                for (int s = 0; s < 6; ++s) {
                    ex += fkU[2*s+1] * v[k+s].x;  ey += fkU[2*s+1] * v[k+s].y;
                    ox += fkU[2*s]   * v[k+s].x;  oy += fkU[2*s]   * v[k+s].y;
                }
                *(float2*)(smem + VS + (2*m)   * VSS + 2*cp) = make_float2(ex, ey);
                *(float2*)(smem + VS + (2*m+1) * VSS + 2*cp) = make_float2(ox, oy);
            }
        }
    }
    __syncthreads();

    // ---- B: horizontal up + lrelu (VS -> ZS f16). task = (row i<74, 16-col chunk q<5) ----
#pragma unroll
    for (int it = 0; it < 2; ++it) {
        int task = tid + 256 * it;
        if (task < 370) {
            int q = task % 5, i = task / 5;
            const float* vp = smem + VS + i * VSS + 8 * q;
            float4 a  = *(const float4*)(vp);
            float4 b  = *(const float4*)(vp + 4);
            float4 cc = *(const float4*)(vp + 8);
            float c12 = vp[12];
            float c[13] = { a.x,a.y,a.z,a.w, b.x,b.y,b.z,b.w, cc.x,cc.y,cc.z,cc.w, c12 };
            unsigned pkz[8];
#pragma unroll
            for (int h = 0; h < 8; ++h) {            // j = 16q+2h (lo), 16q+2h+1 (hi)
                float ze = 0.f, zo = 0.f;
#pragma unroll
                for (int s = 0; s < 6; ++s) {
                    ze += fkU[2*s+1] * c[h+s];
                    zo += fkU[2*s]   * c[h+s];
                }
                ze = fmaxf(ze, 0.01f * ze);
                zo = fmaxf(zo, 0.01f * zo);
                h2 p; p.x = (half_t)ze; p.y = (half_t)zo;
                pkz[h] = h2u(p);
            }
            unsigned* zp = smemu + ZS + i * ZSS + 8 * q;
            *(uint4*)(zp)     = make_uint4(pkz[0], pkz[1], pkz[2], pkz[3]);
            *(uint4*)(zp + 4) = make_uint4(pkz[4], pkz[5], pkz[6], pkz[7]);
        }
    }
    __syncthreads();

    // ---- C: vertical down (ZS f16 -> WS f32), packed f16 FMA, 2 out rows/task ----
    // task = (col-oct p8<10, row-pair hc<16); reads z rows 4hc..4hc+13.
    // Per out row: 12-tap sum split into two 6-tap f16 partials, combined in f32.
    if (tid < 160) {
        int p8 = tid % 10, hc = tid / 10;
        h2 fkh[TAPS];
#pragma unroll
        for (int t = 0; t < TAPS; ++t) {
            half_t v = (half_t)(0.5f * fkU[t]);
            h2 tt; tt.x = v; tt.y = v; fkh[t] = tt;
        }
        h2 zzero; zzero.x = (half_t)0.f; zzero.y = (half_t)0.f;
        h2 a0[4], a1[4], b0[4], b1[4];
#pragma unroll
        for (int d = 0; d < 4; ++d) { a0[d]=zzero; a1[d]=zzero; b0[d]=zzero; b1[d]=zzero; }
        const unsigned* zbase = smemu + ZS + (4 * hc) * ZSS + 4 * p8;
#pragma unroll
        for (int u = 0; u < 14; ++u) {
            uint4 zr = *(const uint4*)(zbase + u * ZSS);
            h2 z0 = u2h(zr.x), z1 = u2h(zr.y), z2 = u2h(zr.z), z3 = u2h(zr.w);
            if (u < 12) {                         // out row 2hc, tap u
                h2 t = fkh[u];
                if (u < 6) { a0[0] += t*z0; a0[1] += t*z1; a0[2] += t*z2; a0[3] += t*z3; }
                else       { a1[0] += t*z0; a1[1] += t*z1; a1[2] += t*z2; a1[3] += t*z3; }
            }
            if (u >= 2) {                         // out row 2hc+1, tap u-2
                h2 t = fkh[u - 2];
                if (u < 8) { b0[0] += t*z0; b0[1] += t*z1; b0[2] += t*z2; b0[3] += t*z3; }
                else       { b1[0] += t*z0; b1[1] += t*z1; b1[2] += t*z2; b1[3] += t*z3; }
            }
        }
        float wa[8], wb[8];
#pragma unroll
        for (int d = 0; d < 4; ++d) {
            wa[2*d]   = (float)a0[d].x + (float)a1[d].x;
            wa[2*d+1] = (float)a0[d].y + (float)a1[d].y;
            wb[2*d]   = (float)b0[d].x + (float)b1[d].x;
            wb[2*d+1] = (float)b0[d].y + (float)b1[d].y;
        }
        float* wp = smem + WS + (2 * hc) * WSS + 8 * p8;
        *(float4*)(wp)           = make_float4(wa[0], wa[1], wa[2], wa[3]);
        *(float4*)(wp + 4)       = make_float4(wa[4], wa[5], wa[6], wa[7]);
        *(float4*)(wp + WSS)     = make_float4(wb[0], wb[1], wb[2], wb[3]);
        *(float4*)(wp + WSS + 4) = make_float4(wb[4], wb[5], wb[6], wb[7]);
    }
    __syncthreads();

    // ---- D: horizontal down (WS -> global). task = (ho = tid>>3, col-quad w4 = tid&7) ----
    {
        float fkD[TAPS];
#pragma unroll
        for (int t = 0; t < TAPS; ++t) fkD[t] = 0.5f * fkU[t];
        int ho = tid >> 3, w4 = tid & 7;
        const float* wp = smem + WS + ho * WSS + 8 * w4;
        float4 r0 = *(const float4*)(wp);
        float4 r1 = *(const float4*)(wp + 4);
        float4 r2 = *(const float4*)(wp + 8);
        float4 r3 = *(const float4*)(wp + 12);
        float2 r4 = *(const float2*)(wp + 16);
        float w[18] = { r0.x,r0.y,r0.z,r0.w, r1.x,r1.y,r1.z,r1.w,
                        r2.x,r2.y,r2.z,r2.w, r3.x,r3.y,r3.z,r3.w, r4.x,r4.y };
        float o[4];
#pragma unroll
        for (int v = 0; v < 4; ++v) {
            float acc = 0.f;
#pragma unroll
            for (int t = 0; t < TAPS; ++t) acc += fkD[t] * w[2 * v + t];
            o[v] = acc;
        }
        *(float4*)(out + ((size_t)nc * 128 + (ho0 + ho)) * 128 + wo0 + 4 * w4)
            = make_float4(o[0], o[1], o[2], o[3]);
    }
}

extern "C" void kernel_launch(void* const* d_in, const int* in_sizes, int n_in,
                              void* d_out, int out_size, void* d_ws, size_t ws_size,
                              hipStream_t stream) {
    const float* x = (const float*)d_in[0];
    const float* f = (const float*)d_in[1];
    float* out = (float*)d_out;
    dim3 grid(16, 1024);
    flrelu_fused<<<grid, 256, 0, stream>>>(x, f, out);
}

// Round 7
// 91.496 us; speedup vs baseline: 1.4615x; 1.1535x over previous
//
#include <hip/hip_runtime.h>

// StyleGAN3 filtered_lrelu, fused. R7 = R6 + LDS live-range overlay:
//   live ranges: XS:[load,A]  VS:[A,B]  ZS:[B,C]  WS:[C,D]
//   peak concurrency = VS+ZS = 6216 dw = 24.9 KB  (was 31.5 KB)
//   -> 6 blocks/CU (24 waves) instead of 5.
// Layout: VS@0(3256), ZS@3256(2960); XS@3256 (inside ZS region, dead before
// B writes ZS); WS@0 (inside VS region, VS dead before C writes WS).
//
// Math (identical to verified R1..R6):
//   fk[t] = f[11-t];  fkU[t] = 2*fk[t]  (per-pass up-gain folded in)
//   up (per axis): out idx i: base=i>>1, tap0=1-(i&1):
//       v[i] = sum_{s<6} fkU[2s+tap0] * src[base+s]
//   leaky relu slope 0.01 between up and down
//   down (per axis): out[o] = sum_{t<12} fk[t] * z[2o+t]

#define TAPS 12
#define VS 0
#define VSS 44
#define ZS 3256
#define ZSS 40
#define XS 3256
#define XSS 44
#define WS 0
#define WSS 84
#define LDS_DW 6216

typedef _Float16 half_t;
typedef half_t h2 __attribute__((ext_vector_type(2)));

__device__ __forceinline__ h2 u2h(unsigned u){ h2 r; __builtin_memcpy(&r, &u, 4); return r; }
__device__ __forceinline__ unsigned h2u(h2 h){ unsigned u; __builtin_memcpy(&u, &h, 4); return u; }

__global__ __launch_bounds__(256) void flrelu_fused(
    const float* __restrict__ x, const float* __restrict__ f, float* __restrict__ out)
{
    __shared__ float smem[LDS_DW];
    unsigned* smemu = reinterpret_cast<unsigned*>(smem);

    const int tid = threadIdx.x;
    const int nc  = blockIdx.y;
    const int ho0 = (blockIdx.x >> 2) * 32;
    const int wo0 = (blockIdx.x & 3) * 32;

    // fkU[t] = 2 * f[11-t]  (up-stage taps with gain folded)
    float fkU[TAPS];
#pragma unroll
    for (int t = 0; t < TAPS; ++t) fkU[t] = 2.0f * f[TAPS - 1 - t];

    const float* xin = x + (size_t)nc * (128 * 128);

    // ---- halo load: 42x42 fp32 -> XS ----
#pragma unroll
    for (int k = 0; k < 7; ++k) {
        int e = tid + 256 * k;
        if (e < 42 * 42) {
            int r = e / 42, c = e - r * 42;
            int gr = ho0 - 5 + r, gc = wo0 - 5 + c;
            float v = 0.f;
            if ((unsigned)gr < 128u && (unsigned)gc < 128u) v = xin[gr * 128 + gc];
            smem[XS + r * XSS + c] = v;
        }
    }
    __syncthreads();

    // ---- A: vertical up (XS -> VS). task = (col-pair cp<21, m-chunk mc<10) ----
    if (tid < 210) {
        int cp = tid % 21, mc = tid / 21;
        int m0 = mc * 4;
        float2 v[9];
#pragma unroll
        for (int s = 0; s < 9; ++s) {
            int r = m0 + s; r = r < 42 ? r : 41;      // clamped rows feed only skipped m
            v[s] = *(const float2*)(smem + XS + r * XSS + 2 * cp);
        }
#pragma unroll
        for (int k = 0; k < 4; ++k) {
            int m = m0 + k;
            if (m < 37) {
                float ex = 0.f, ey = 0.f, ox = 0.f, oy = 0.f;
#pragma unroll
                for (int s = 0; s < 6; ++s) {
                    ex += fkU[2*s+1] * v[k+s].x;  ey += fkU[2*s+1] * v[k+s].y;
                    ox += fkU[2*s]   * v[k+s].x;  oy += fkU[2*s]   * v[k+s].y;
                }
                *(float2*)(smem + VS + (2*m)   * VSS + 2*cp) = make_float2(ex, ey);
                *(float2*)(smem + VS + (2*m+1) * VSS + 2*cp) = make_float2(ox, oy);
            }
        }
    }
    __syncthreads();

    // ---- B: horizontal up + lrelu (VS -> ZS f16). task = (row i<74, 16-col chunk q<5) ----
#pragma unroll
    for (int it = 0; it < 2; ++it) {
        int task = tid + 256 * it;
        if (task < 370) {
            int q = task % 5, i = task / 5;
            const float* vp = smem + VS + i * VSS + 8 * q;
            float4 a  = *(const float4*)(vp);
            float4 b  = *(const float4*)(vp + 4);
            float4 cc = *(const float4*)(vp + 8);
            float c12 = vp[12];
            float c[13] = { a.x,a.y,a.z,a.w, b.x,b.y,b.z,b.w, cc.x,cc.y,cc.z,cc.w, c12 };
            unsigned pkz[8];
#pragma unroll
            for (int h = 0; h < 8; ++h) {            // j = 16q+2h (lo), 16q+2h+1 (hi)
                float ze = 0.f, zo = 0.f;
#pragma unroll
                for (int s = 0; s < 6; ++s) {
                    ze += fkU[2*s+1] * c[h+s];
                    zo += fkU[2*s]   * c[h+s];
                }
                ze = fmaxf(ze, 0.01f * ze);
                zo = fmaxf(zo, 0.01f * zo);
                h2 p; p.x = (half_t)ze; p.y = (half_t)zo;
                pkz[h] = h2u(p);
            }
            unsigned* zp = smemu + ZS + i * ZSS + 8 * q;
            *(uint4*)(zp)     = make_uint4(pkz[0], pkz[1], pkz[2], pkz[3]);
            *(uint4*)(zp + 4) = make_uint4(pkz[4], pkz[5], pkz[6], pkz[7]);
        }
    }
    __syncthreads();

    // ---- C: vertical down (ZS f16 -> WS f32), packed f16 FMA, 2 out rows/task ----
    // task = (col-oct p8<10, row-pair hc<16); reads z rows 4hc..4hc+13.
    // Per out row: 12-tap sum split into two 6-tap f16 partials, combined in f32.
    if (tid < 160) {
        int p8 = tid % 10, hc = tid / 10;
        h2 fkh[TAPS];
#pragma unroll
        for (int t = 0; t < TAPS; ++t) {
            half_t v = (half_t)(0.5f * fkU[t]);
            h2 tt; tt.x = v; tt.y = v; fkh[t] = tt;
        }
        h2 zzero; zzero.x = (half_t)0.f; zzero.y = (half_t)0.f;
        h2 a0[4], a1[4], b0[4], b1[4];
#pragma unroll
        for (int d = 0; d < 4; ++d) { a0[d]=zzero; a1[d]=zzero; b0[d]=zzero; b1[d]=zzero; }
        const unsigned* zbase = smemu + ZS + (4 * hc) * ZSS + 4 * p8;
#pragma unroll
        for (int u = 0; u < 14; ++u) {
            uint4 zr = *(const uint4*)(zbase + u * ZSS);
            h2 z0 = u2h(zr.x), z1 = u2h(zr.y), z2 = u2h(zr.z), z3 = u2h(zr.w);
            if (u < 12) {                         // out row 2hc, tap u
                h2 t = fkh[u];
                if (u < 6) { a0[0] += t*z0; a0[1] += t*z1; a0[2] += t*z2; a0[3] += t*z3; }
                else       { a1[0] += t*z0; a1[1] += t*z1; a1[2] += t*z2; a1[3] += t*z3; }
            }
            if (u >= 2) {                         // out row 2hc+1, tap u-2
                h2 t = fkh[u - 2];
                if (u < 8) { b0[0] += t*z0; b0[1] += t*z1; b0[2] += t*z2; b0[3] += t*z3; }
                else       { b1[0] += t*z0; b1[1] += t*z1; b1[2] += t*z2; b1[3] += t*z3; }
            }
        }
        float wa[8], wb[8];
#pragma unroll
        for (int d = 0; d < 4; ++d) {
            wa[2*d]   = (float)a0[d].x + (float)a1[d].x;
            wa[2*d+1] = (float)a0[d].y + (float)a1[d].y;
            wb[2*d]   = (float)b0[d].x + (float)b1[d].x;
            wb[2*d+1] = (float)b0[d].y + (float)b1[d].y;
        }
        float* wp = smem + WS + (2 * hc) * WSS + 8 * p8;
        *(float4*)(wp)           = make_float4(wa[0], wa[1], wa[2], wa[3]);
        *(float4*)(wp + 4)       = make_float4(wa[4], wa[5], wa[6], wa[7]);
        *(float4*)(wp + WSS)     = make_float4(wb[0], wb[1], wb[2], wb[3]);
        *(float4*)(wp + WSS + 4) = make_float4(wb[4], wb[5], wb[6], wb[7]);
    }
    __syncthreads();

    // ---- D: horizontal down (WS -> global). task = (ho = tid>>3, col-quad w4 = tid&7) ----
    {
        float fkD[TAPS];
#pragma unroll
        for (int t = 0; t < TAPS; ++t) fkD[t] = 0.5f * fkU[t];
        int ho = tid >> 3, w4 = tid & 7;
        const float* wp = smem + WS + ho * WSS + 8 * w4;
        float4 r0 = *(const float4*)(wp);
        float4 r1 = *(const float4*)(wp + 4);
        float4 r2 = *(const float4*)(wp + 8);
        float4 r3 = *(const float4*)(wp + 12);
        float2 r4 = *(const float2*)(wp + 16);
        float w[18] = { r0.x,r0.y,r0.z,r0.w, r1.x,r1.y,r1.z,r1.w,
                        r2.x,r2.y,r2.z,r2.w, r3.x,r3.y,r3.z,r3.w, r4.x,r4.y };
        float o[4];
#pragma unroll
        for (int v = 0; v < 4; ++v) {
            float acc = 0.f;
#pragma unroll
            for (int t = 0; t < TAPS; ++t) acc += fkD[t] * w[2 * v + t];
            o[v] = acc;
        }
        *(float4*)(out + ((size_t)nc * 128 + (ho0 + ho)) * 128 + wo0 + 4 * w4)
            = make_float4(o[0], o[1], o[2], o[3]);
    }
}

extern "C" void kernel_launch(void* const* d_in, const int* in_sizes, int n_in,
                              void* d_out, int out_size, void* d_ws, size_t ws_size,
                              hipStream_t stream) {
    const float* x = (const float*)d_in[0];
    const float* f = (const float*)d_in[1];
    float* out = (float*)d_out;
    dim3 grid(16, 1024);
    flrelu_fused<<<grid, 256, 0, stream>>>(x, f, out);
}

// Round 9
// 80.381 us; speedup vs baseline: 1.6636x; 1.1383x over previous
//
#include <hip/hip_runtime.h>

// StyleGAN3 filtered_lrelu, fused. R9 = R8 with cvt_pkrtz type fix.
//   A: packed f32 FMA over output parity, b128 XS reads, VS2 stores
//      v as (even,odd) float2 pairs.
//   B: one task computes BOTH z-rows 2m,2m+1 from one VS2 row; packed f32
//      FMA over the parity axis; cvt_pkrtz packs f16 pairs in 1 instr.
//   Strides: VS2 row = 92 dw (odd quad-step -> conflict-free B reads),
//            ZS  row = 44 dw (odd quad-step -> conflict-free C reads).
//
// Math (identical to verified R1..R7):
//   fk[t] = f[11-t];  fkU[t] = 2*fk[t]
//   up (per axis): v[i] = sum_{s<6} fkU[2s + (1-(i&1))] * src[(i>>1)+s]
//   leaky relu slope 0.01 between up and down
//   down (per axis): out[o] = sum_{t<12} fk[t] * z[2o+t]
//
// Tile 32x32 out / block, 256 threads. LDS (dwords):
//   VS2 [37][92] f32x2 @0     (vert-up, even/odd interleaved; dead after B)
//   ZS  [74][44] f16x2 @3404  (up+lrelu; cols>=74 garbage-ok, D reads <=73)
//   XS  [42][44] f32  @3404   (halo; inside ZS region, dead before B writes)
//   WS  [32][84] f32  @0      (vert-down; inside VS2 region, VS2 dead by C)
// total 6660 dw = 26640 B -> 6 blocks/CU.

#define TAPS 12
#define VS2 0
#define VSS2 92
#define ZS 3404
#define ZSS 44
#define XS 3404
#define XSS 44
#define WS 0
#define WSS 84
#define LDS_DW 6660

typedef _Float16 half_t;
typedef half_t h2 __attribute__((ext_vector_type(2)));
typedef float f2 __attribute__((ext_vector_type(2)));

__device__ __forceinline__ h2 u2h(unsigned u){ h2 r; __builtin_memcpy(&r, &u, 4); return r; }
__device__ __forceinline__ unsigned h2du(h2 h){ unsigned u; __builtin_memcpy(&u, &h, 4); return u; }
__device__ __forceinline__ unsigned pkrtz_u(float lo, float hi){
    auto p = __builtin_amdgcn_cvt_pkrtz(lo, hi);   // __fp16 ext_vector(2)
    unsigned u; __builtin_memcpy(&u, &p, 4); return u;
}

__global__ __launch_bounds__(256) void flrelu_fused(
    const float* __restrict__ x, const float* __restrict__ f, float* __restrict__ out)
{
    __shared__ float smem[LDS_DW];
    unsigned* smemu = reinterpret_cast<unsigned*>(smem);

    const int tid = threadIdx.x;
    const int nc  = blockIdx.y;
    const int ho0 = (blockIdx.x >> 2) * 32;
    const int wo0 = (blockIdx.x & 3) * 32;

    // fkU[t] = 2 * f[11-t]  (up-stage taps with gain folded)
    float fkU[TAPS];
#pragma unroll
    for (int t = 0; t < TAPS; ++t) fkU[t] = 2.0f * f[TAPS - 1 - t];

    const float* xin = x + (size_t)nc * (128 * 128);

    // ---- halo load: 42x42 fp32 -> XS ----
#pragma unroll
    for (int k = 0; k < 7; ++k) {
        int e = tid + 256 * k;
        if (e < 42 * 42) {
            int r = e / 42, c = e - r * 42;
            int gr = ho0 - 5 + r, gc = wo0 - 5 + c;
            float v = 0.f;
            if ((unsigned)gr < 128u && (unsigned)gc < 128u) v = xin[gr * 128 + gc];
            smem[XS + r * XSS + c] = v;
        }
    }
    __syncthreads();

    // ---- A: vertical up (XS -> VS2 packed). task = (col-quad cq<11, mc<19) ----
    // computes v[2m], v[2m+1] for m = 2mc, 2mc+1 at cols 4cq..4cq+3;
    // VS2[m][c] = (v[2m][c], v[2m+1][c]).
    if (tid < 209) {
        int cq = tid % 11, mc = tid / 11;
        float4 xv[7];
#pragma unroll
        for (int s = 0; s < 7; ++s) {
            int r = 2 * mc + s; r = r < 42 ? r : 41;   // clamped row feeds only skipped m
            xv[s] = *(const float4*)(smem + XS + r * XSS + 4 * cq);
        }
        f2 tap2[6];
#pragma unroll
        for (int s = 0; s < 6; ++s) { tap2[s].x = fkU[2*s+1]; tap2[s].y = fkU[2*s]; }
#pragma unroll
        for (int k2 = 0; k2 < 2; ++k2) {
            int m = 2 * mc + k2;
            if (m < 37) {
                f2 acc[4];
#pragma unroll
                for (int c = 0; c < 4; ++c) { acc[c].x = 0.f; acc[c].y = 0.f; }
#pragma unroll
                for (int s = 0; s < 6; ++s) {
                    float4 xr = xv[k2 + s];
                    acc[0] += tap2[s] * xr.x;
                    acc[1] += tap2[s] * xr.y;
                    acc[2] += tap2[s] * xr.z;
                    acc[3] += tap2[s] * xr.w;
                }
                float* vp = smem + VS2 + m * VSS2 + 8 * cq;
                *(float4*)(vp)     = make_float4(acc[0].x, acc[0].y, acc[1].x, acc[1].y);
                *(float4*)(vp + 4) = make_float4(acc[2].x, acc[2].y, acc[3].x, acc[3].y);
            }
        }
    }
    __syncthreads();

    // ---- B: horizontal up + lrelu (VS2 -> ZS f16). task = (m<37, 16-col chunk q<5) ----
    // one task -> z rows 2m and 2m+1, cols 16q..16q+15.
    if (tid < 185) {
        int q = tid % 5, m = tid / 5;
        const float* vp = smem + VS2 + m * VSS2 + 16 * q;
        f2 vc[14];
#pragma unroll
        for (int j = 0; j < 7; ++j) {
            float4 rd = *(const float4*)(vp + 4 * j);
            vc[2*j].x = rd.x;   vc[2*j].y = rd.y;
            vc[2*j+1].x = rd.z; vc[2*j+1].y = rd.w;
        }
        unsigned pk0[8], pk1[8];
#pragma unroll
        for (int h = 0; h < 8; ++h) {        // z cols 16q+2h (even), 16q+2h+1 (odd)
            f2 ae; ae.x = 0.f; ae.y = 0.f;   // .x -> row 2m, .y -> row 2m+1
            f2 ao; ao.x = 0.f; ao.y = 0.f;
#pragma unroll
            for (int s = 0; s < 6; ++s) {
                ae += vc[h + s] * fkU[2*s+1];
                ao += vc[h + s] * fkU[2*s];
            }
            f2 me = ae * 0.01f, mo = ao * 0.01f;
            ae.x = fmaxf(ae.x, me.x); ae.y = fmaxf(ae.y, me.y);
            ao.x = fmaxf(ao.x, mo.x); ao.y = fmaxf(ao.y, mo.y);
            pk0[h] = pkrtz_u(ae.x, ao.x);    // row 2m:   (z_even, z_odd)
            pk1[h] = pkrtz_u(ae.y, ao.y);    // row 2m+1: (z_even, z_odd)
        }
        unsigned* z0 = smemu + ZS + (2 * m) * ZSS + 8 * q;
        unsigned* z1 = z0 + ZSS;
        *(uint4*)(z0)     = make_uint4(pk0[0], pk0[1], pk0[2], pk0[3]);
        *(uint4*)(z0 + 4) = make_uint4(pk0[4], pk0[5], pk0[6], pk0[7]);
        *(uint4*)(z1)     = make_uint4(pk1[0], pk1[1], pk1[2], pk1[3]);
        *(uint4*)(z1 + 4) = make_uint4(pk1[4], pk1[5], pk1[6], pk1[7]);
    }
    __syncthreads();

    // ---- C: vertical down (ZS f16 -> WS f32), packed f16 FMA, 2 out rows/task ----
    // task = (col-oct p8<10, row-pair hc<16); reads z rows 4hc..4hc+13.
    if (tid < 160) {
        int p8 = tid % 10, hc = tid / 10;
        h2 fkh[TAPS];
#pragma unroll
        for (int t = 0; t < TAPS; ++t) {
            half_t v = (half_t)(0.5f * fkU[t]);
            h2 tt; tt.x = v; tt.y = v; fkh[t] = tt;
        }
        h2 zzero; zzero.x = (half_t)0.f; zzero.y = (half_t)0.f;
        h2 a0[4], a1[4], b0[4], b1[4];
#pragma unroll
        for (int d = 0; d < 4; ++d) { a0[d]=zzero; a1[d]=zzero; b0[d]=zzero; b1[d]=zzero; }
        const unsigned* zbase = smemu + ZS + (4 * hc) * ZSS + 4 * p8;
#pragma unroll
        for (int u = 0; u < 14; ++u) {
            uint4 zr = *(const uint4*)(zbase + u * ZSS);
            h2 z0 = u2h(zr.x), z1 = u2h(zr.y), z2 = u2h(zr.z), z3 = u2h(zr.w);
            if (u < 12) {                         // out row 2hc, tap u
                h2 t = fkh[u];
                if (u < 6) { a0[0] += t*z0; a0[1] += t*z1; a0[2] += t*z2; a0[3] += t*z3; }
                else       { a1[0] += t*z0; a1[1] += t*z1; a1[2] += t*z2; a1[3] += t*z3; }
            }
            if (u >= 2) {                         // out row 2hc+1, tap u-2
                h2 t = fkh[u - 2];
                if (u < 8) { b0[0] += t*z0; b0[1] += t*z1; b0[2] += t*z2; b0[3] += t*z3; }
                else       { b1[0] += t*z0; b1[1] += t*z1; b1[2] += t*z2; b1[3] += t*z3; }
            }
        }
        float wa[8], wb[8];
#pragma unroll
        for (int d = 0; d < 4; ++d) {
            wa[2*d]   = (float)a0[d].x + (float)a1[d].x;
            wa[2*d+1] = (float)a0[d].y + (float)a1[d].y;
            wb[2*d]   = (float)b0[d].x + (float)b1[d].x;
            wb[2*d+1] = (float)b0[d].y + (float)b1[d].y;
        }
        float* wp = smem + WS + (2 * hc) * WSS + 8 * p8;
        *(float4*)(wp)           = make_float4(wa[0], wa[1], wa[2], wa[3]);
        *(float4*)(wp + 4)       = make_float4(wa[4], wa[5], wa[6], wa[7]);
        *(float4*)(wp + WSS)     = make_float4(wb[0], wb[1], wb[2], wb[3]);
        *(float4*)(wp + WSS + 4) = make_float4(wb[4], wb[5], wb[6], wb[7]);
    }
    __syncthreads();

    // ---- D: horizontal down (WS -> global). task = (ho = tid>>3, col-quad w4 = tid&7) ----
    {
        float fkD[TAPS];
#pragma unroll
        for (int t = 0; t < TAPS; ++t) fkD[t] = 0.5f * fkU[t];
        int ho = tid >> 3, w4 = tid & 7;
        const float* wp = smem + WS + ho * WSS + 8 * w4;
        float4 r0 = *(const float4*)(wp);
        float4 r1 = *(const float4*)(wp + 4);
        float4 r2 = *(const float4*)(wp + 8);
        float4 r3 = *(const float4*)(wp + 12);
        float2 r4 = *(const float2*)(wp + 16);
        float w[18] = { r0.x,r0.y,r0.z,r0.w, r1.x,r1.y,r1.z,r1.w,
                        r2.x,r2.y,r2.z,r2.w, r3.x,r3.y,r3.z,r3.w, r4.x,r4.y };
        float o[4];
#pragma unroll
        for (int v = 0; v < 4; ++v) {
            float acc = 0.f;
#pragma unroll
            for (int t = 0; t < TAPS; ++t) acc += fkD[t] * w[2 * v + t];
            o[v] = acc;
        }
        *(float4*)(out + ((size_t)nc * 128 + (ho0 + ho)) * 128 + wo0 + 4 * w4)
            = make_float4(o[0], o[1], o[2], o[3]);
    }
}

extern "C" void kernel_launch(void* const* d_in, const int* in_sizes, int n_in,
                              void* d_out, int out_size, void* d_ws, size_t ws_size,
                              hipStream_t stream) {
    const float* x = (const float*)d_in[0];
    const float* f = (const float*)d_in[1];
    float* out = (float*)d_out;
    dim3 grid(16, 1024);
    flrelu_fused<<<grid, 256, 0, stream>>>(x, f, out);
}

// Round 10
// 71.310 us; speedup vs baseline: 1.8752x; 1.1272x over previous
//
#include <hip/hip_runtime.h>

// StyleGAN3 filtered_lrelu, fused. R10 = R9 with ALL intermediates in f16:
//   VS2 [37][44] f16x2 (row-parity pairs)  -> B reads 4 (not 7) b128
//   ZS  [74][44] f16x2 (col-parity pairs)  -> unchanged layout
//   WS  [32][44] f16x2 (col-parity pairs)  -> C writes 2 (not 4), D reads 3 (not 5)
// Peak LDS = VS2+ZS = 4884 dw = 19536 B -> 8 blocks/CU (32 waves, 100% occ).
// B compute in packed v_pk_fma_f16; lrelu via v_pk_max_f16.
//
// Math (identical to verified R1..R9):
//   fk[t] = f[11-t];  fkU[t] = 2*fk[t]
//   up (per axis): v[i] = sum_{s<6} fkU[2s + (1-(i&1))] * src[(i>>1)+s]
//   leaky relu slope 0.01 between up and down
//   down (per axis): out[o] = sum_{t<12} fk[t] * z[2o+t]
//
// LDS layout (dwords): VS2@0 (1628), ZS@1628 (3256), XS@1628 f32 42x44 (1848,
// halo, dead before B writes ZS), WS@0 (1408, VS2 dead by C). total 4884 dw.
// B's chunk q=4 reads up to 14 dw past col 41 (garbage) -> feeds only z cols
// >73 which are never consumed; max overrun lands in ZS region (no fault).

#define TAPS 12
#define VS2 0
#define VSS2 44
#define ZS 1628
#define ZSS 44
#define XS 1628
#define XSS 44
#define WS 0
#define WSS 44
#define LDS_DW 4884

typedef _Float16 half_t;
typedef half_t h2 __attribute__((ext_vector_type(2)));
typedef float f2 __attribute__((ext_vector_type(2)));

__device__ __forceinline__ h2 u2h(unsigned u){ h2 r; __builtin_memcpy(&r, &u, 4); return r; }
__device__ __forceinline__ unsigned h2du(h2 h){ unsigned u; __builtin_memcpy(&u, &h, 4); return u; }
__device__ __forceinline__ unsigned pkrtz_u(float lo, float hi){
    auto p = __builtin_amdgcn_cvt_pkrtz(lo, hi);
    unsigned u; __builtin_memcpy(&u, &p, 4); return u;
}
__device__ __forceinline__ h2 h2s(float v){ h2 r; r.x = (half_t)v; r.y = r.x; return r; }
__device__ __forceinline__ unsigned pack2(half_t a, half_t b){ h2 t; t.x=a; t.y=b; return h2du(t); }

__global__ __launch_bounds__(256) void flrelu_fused(
    const float* __restrict__ x, const float* __restrict__ f, float* __restrict__ out)
{
    __shared__ float smem[LDS_DW];
    unsigned* smemu = reinterpret_cast<unsigned*>(smem);

    const int tid = threadIdx.x;
    const int nc  = blockIdx.y;
    const int ho0 = (blockIdx.x >> 2) * 32;
    const int wo0 = (blockIdx.x & 3) * 32;

    float fkU[TAPS];
#pragma unroll
    for (int t = 0; t < TAPS; ++t) fkU[t] = 2.0f * f[TAPS - 1 - t];

    const float* xin = x + (size_t)nc * (128 * 128);

    // ---- halo load: 42x42 fp32 -> XS ----
#pragma unroll
    for (int k = 0; k < 7; ++k) {
        int e = tid + 256 * k;
        if (e < 42 * 42) {
            int r = e / 42, c = e - r * 42;
            int gr = ho0 - 5 + r, gc = wo0 - 5 + c;
            float v = 0.f;
            if ((unsigned)gr < 128u && (unsigned)gc < 128u) v = xin[gr * 128 + gc];
            smem[XS + r * XSS + c] = v;
        }
    }
    __syncthreads();

    // ---- A: vertical up (XS f32 -> VS2 f16 parity pairs). task=(cq<11, mc<19) ----
    // VS2[m][c] = h2(v[2m][c], v[2m+1][c]); writes 1 b128 per m (cols 4cq..4cq+3).
    if (tid < 209) {
        int cq = tid % 11, mc = tid / 11;
        float4 xv[7];
#pragma unroll
        for (int s = 0; s < 7; ++s) {
            int r = 2 * mc + s; r = r < 42 ? r : 41;   // clamped row feeds only skipped m
            xv[s] = *(const float4*)(smem + XS + r * XSS + 4 * cq);
        }
        f2 tap2[6];
#pragma unroll
        for (int s = 0; s < 6; ++s) { tap2[s].x = fkU[2*s+1]; tap2[s].y = fkU[2*s]; }
#pragma unroll
        for (int k2 = 0; k2 < 2; ++k2) {
            int m = 2 * mc + k2;
            if (m < 37) {
                f2 acc[4];
#pragma unroll
                for (int c = 0; c < 4; ++c) { acc[c].x = 0.f; acc[c].y = 0.f; }
#pragma unroll
                for (int s = 0; s < 6; ++s) {
                    float4 xr = xv[k2 + s];
                    acc[0] += tap2[s] * xr.x;
                    acc[1] += tap2[s] * xr.y;
                    acc[2] += tap2[s] * xr.z;
                    acc[3] += tap2[s] * xr.w;
                }
                unsigned* vp = smemu + VS2 + m * VSS2 + 4 * cq;
                *(uint4*)vp = make_uint4(pkrtz_u(acc[0].x, acc[0].y),
                                         pkrtz_u(acc[1].x, acc[1].y),
                                         pkrtz_u(acc[2].x, acc[2].y),
                                         pkrtz_u(acc[3].x, acc[3].y));
            }
        }
    }
    __syncthreads();

    // ---- B: horizontal up + lrelu (VS2 f16 -> ZS f16), packed f16 FMA ----
    // task=(m<37, chunk q<5): z rows 2m,2m+1, cols 16q..16q+15.
    if (tid < 185) {
        int q = tid % 5, m = tid / 5;
        const unsigned* vb = smemu + VS2 + m * VSS2 + 8 * q;
        uint4 r0 = *(const uint4*)(vb);
        uint4 r1 = *(const uint4*)(vb + 4);
        uint4 r2 = *(const uint4*)(vb + 8);
        uint2 r3 = *(const uint2*)(vb + 12);
        h2 vc[14] = { u2h(r0.x), u2h(r0.y), u2h(r0.z), u2h(r0.w),
                      u2h(r1.x), u2h(r1.y), u2h(r1.z), u2h(r1.w),
                      u2h(r2.x), u2h(r2.y), u2h(r2.z), u2h(r2.w),
                      u2h(r3.x), u2h(r3.y) };
        h2 fo[6], fe[6];
#pragma unroll
        for (int s = 0; s < 6; ++s) { fo[s] = h2s(fkU[2*s+1]); fe[s] = h2s(fkU[2*s]); }
        h2 sl = h2s(0.01f);
        unsigned pk0[8], pk1[8];
#pragma unroll
        for (int h = 0; h < 8; ++h) {        // z cols 16q+2h (even), +1 (odd)
            h2 ae = h2s(0.f), ao = h2s(0.f); // lanes: .x=row 2m, .y=row 2m+1
#pragma unroll
            for (int s = 0; s < 6; ++s) {
                ae += vc[h + s] * fo[s];
                ao += vc[h + s] * fe[s];
            }
            ae = __builtin_elementwise_max(ae, ae * sl);
            ao = __builtin_elementwise_max(ao, ao * sl);
            pk0[h] = pack2(ae.x, ao.x);      // row 2m:   (z_even, z_odd)
            pk1[h] = pack2(ae.y, ao.y);      // row 2m+1: (z_even, z_odd)
        }
        unsigned* z0 = smemu + ZS + (2 * m) * ZSS + 8 * q;
        unsigned* z1 = z0 + ZSS;
        *(uint4*)(z0)     = make_uint4(pk0[0], pk0[1], pk0[2], pk0[3]);
        *(uint4*)(z0 + 4) = make_uint4(pk0[4], pk0[5], pk0[6], pk0[7]);
        *(uint4*)(z1)     = make_uint4(pk1[0], pk1[1], pk1[2], pk1[3]);
        *(uint4*)(z1 + 4) = make_uint4(pk1[4], pk1[5], pk1[6], pk1[7]);
    }
    __syncthreads();

    // ---- C: vertical down (ZS f16 -> WS f16), packed f16 FMA, 2 out rows/task ----
    // task=(col-oct p8<10, row-pair hc<16); reads z rows 4hc..4hc+13.
    if (tid < 160) {
        int p8 = tid % 10, hc = tid / 10;
        h2 fkh[TAPS];
#pragma unroll
        for (int t = 0; t < TAPS; ++t) fkh[t] = h2s(0.5f * fkU[t]);
        h2 zzero = h2s(0.f);
        h2 a0[4], a1[4], b0[4], b1[4];
#pragma unroll
        for (int d = 0; d < 4; ++d) { a0[d]=zzero; a1[d]=zzero; b0[d]=zzero; b1[d]=zzero; }
        const unsigned* zbase = smemu + ZS + (4 * hc) * ZSS + 4 * p8;
#pragma unroll
        for (int u = 0; u < 14; ++u) {
            uint4 zr = *(const uint4*)(zbase + u * ZSS);
            h2 z0 = u2h(zr.x), z1 = u2h(zr.y), z2 = u2h(zr.z), z3 = u2h(zr.w);
            if (u < 12) {                         // out row 2hc, tap u
                h2 t = fkh[u];
                if (u < 6) { a0[0] += t*z0; a0[1] += t*z1; a0[2] += t*z2; a0[3] += t*z3; }
                else       { a1[0] += t*z0; a1[1] += t*z1; a1[2] += t*z2; a1[3] += t*z3; }
            }
            if (u >= 2) {                         // out row 2hc+1, tap u-2
                h2 t = fkh[u - 2];
                if (u < 8) { b0[0] += t*z0; b0[1] += t*z1; b0[2] += t*z2; b0[3] += t*z3; }
                else       { b1[0] += t*z0; b1[1] += t*z1; b1[2] += t*z2; b1[3] += t*z3; }
            }
        }
        unsigned* wp = smemu + WS + (2 * hc) * WSS + 4 * p8;
        *(uint4*)(wp)       = make_uint4(h2du(a0[0]+a1[0]), h2du(a0[1]+a1[1]),
                                         h2du(a0[2]+a1[2]), h2du(a0[3]+a1[3]));
        *(uint4*)(wp + WSS) = make_uint4(h2du(b0[0]+b1[0]), h2du(b0[1]+b1[1]),
                                         h2du(b0[2]+b1[2]), h2du(b0[3]+b1[3]));
    }
    __syncthreads();

    // ---- D: horizontal down (WS f16 -> global f32). task=(ho=tid>>3, w4=tid&7) ----
    {
        float fkD[TAPS];
#pragma unroll
        for (int t = 0; t < TAPS; ++t) fkD[t] = 0.5f * fkU[t];
        int ho = tid >> 3, w4 = tid & 7;
        const unsigned* wp = smemu + WS + ho * WSS + 4 * w4;
        uint4 q0 = *(const uint4*)(wp);
        uint4 q1 = *(const uint4*)(wp + 4);
        unsigned q2 = wp[8];
        unsigned dws[9] = { q0.x, q0.y, q0.z, q0.w, q1.x, q1.y, q1.z, q1.w, q2 };
        float w[18];
#pragma unroll
        for (int d = 0; d < 9; ++d) {
            h2 hh = u2h(dws[d]);
            w[2*d]   = (float)hh.x;
            w[2*d+1] = (float)hh.y;
        }
        float o[4];
#pragma unroll
        for (int v = 0; v < 4; ++v) {
            float acc = 0.f;
#pragma unroll
            for (int t = 0; t < TAPS; ++t) acc += fkD[t] * w[2 * v + t];
            o[v] = acc;
        }
        *(float4*)(out + ((size_t)nc * 128 + (ho0 + ho)) * 128 + wo0 + 4 * w4)
            = make_float4(o[0], o[1], o[2], o[3]);
    }
}

extern "C" void kernel_launch(void* const* d_in, const int* in_sizes, int n_in,
                              void* d_out, int out_size, void* d_ws, size_t ws_size,
                              hipStream_t stream) {
    const float* x = (const float*)d_in[0];
    const float* f = (const float*)d_in[1];
    float* out = (float*)d_out;
    dim3 grid(16, 1024);
    flrelu_fused<<<grid, 256, 0, stream>>>(x, f, out);
}

// Round 11
// 60.282 us; speedup vs baseline: 2.2183x; 1.1829x over previous
//
#include <hip/hip_runtime.h>

// StyleGAN3 filtered_lrelu, fused. R11 = R10 + instruction-count cuts:
//   D: v_dot2_f32_f16 (6 fdot2/output, f32 accum) replaces unpack+scalar FMA.
//   halo: one div at entry, clamped-address loads, cndmask zero-fill.
//   C: 4 output rows per task (18 b128 reads / 4 rows), single f16 acc.
// LDS layout unchanged: peak VS2+ZS = 4884 dw = 19.5 KB -> 8 blocks/CU.
//
// Math (identical to verified R1..R10):
//   fk[t] = f[11-t];  fkU[t] = 2*fk[t]
//   up (per axis): v[i] = sum_{s<6} fkU[2s + (1-(i&1))] * src[(i>>1)+s]
//   leaky relu slope 0.01 between up and down
//   down (per axis): out[o] = sum_{t<12} fk[t] * z[2o+t]
//
// LDS (dwords): VS2@0 [37][44] f16x2 row-parity; ZS@1628 [74][44] f16x2
// col-parity; XS@1628 f32 [42][44] (halo, dead before B writes ZS);
// WS@0 [32][44] f16x2 col-parity (VS2 dead by C). total 4884 dw.

#define TAPS 12
#define VS2 0
#define VSS2 44
#define ZS 1628
#define ZSS 44
#define XS 1628
#define XSS 44
#define WS 0
#define WSS 44
#define LDS_DW 4884

typedef _Float16 half_t;
typedef half_t h2 __attribute__((ext_vector_type(2)));
typedef __fp16 g2 __attribute__((ext_vector_type(2)));
typedef float f2 __attribute__((ext_vector_type(2)));

__device__ __forceinline__ h2 u2h(unsigned u){ h2 r; __builtin_memcpy(&r, &u, 4); return r; }
__device__ __forceinline__ g2 u2g(unsigned u){ g2 r; __builtin_memcpy(&r, &u, 4); return r; }
__device__ __forceinline__ unsigned h2du(h2 h){ unsigned u; __builtin_memcpy(&u, &h, 4); return u; }
__device__ __forceinline__ unsigned pkrtz_u(float lo, float hi){
    g2 p = __builtin_amdgcn_cvt_pkrtz(lo, hi);
    unsigned u; __builtin_memcpy(&u, &p, 4); return u;
}
__device__ __forceinline__ h2 h2s(float v){ h2 r; r.x = (half_t)v; r.y = r.x; return r; }
__device__ __forceinline__ unsigned pack2(half_t a, half_t b){ h2 t; t.x=a; t.y=b; return h2du(t); }

__global__ __launch_bounds__(256) void flrelu_fused(
    const float* __restrict__ x, const float* __restrict__ f, float* __restrict__ out)
{
    __shared__ float smem[LDS_DW];
    unsigned* smemu = reinterpret_cast<unsigned*>(smem);

    const int tid = threadIdx.x;
    const int nc  = blockIdx.y;
    const int ho0 = (blockIdx.x >> 2) * 32;
    const int wo0 = (blockIdx.x & 3) * 32;

    float fkU[TAPS];
#pragma unroll
    for (int t = 0; t < TAPS; ++t) fkU[t] = 2.0f * f[TAPS - 1 - t];

    const float* xin = x + (size_t)nc * (128 * 128);

    // ---- halo load: 42x42 fp32 -> XS. task: col c = tid%42, rows r0+6k ----
    if (tid < 252) {
        int c = tid % 42, r0 = tid / 42;
        int gc = wo0 - 5 + c;
        bool gcok = (unsigned)gc < 128u;
        int gcc = gc < 0 ? 0 : (gc > 127 ? 127 : gc);
#pragma unroll
        for (int k = 0; k < 7; ++k) {
            int r = r0 + 6 * k;
            int gr = ho0 - 5 + r;
            int grc = gr < 0 ? 0 : (gr > 127 ? 127 : gr);
            float v = xin[grc * 128 + gcc];
            bool ok = gcok && ((unsigned)gr < 128u);
            smem[XS + r * XSS + c] = ok ? v : 0.f;
        }
    }
    __syncthreads();

    // ---- A: vertical up (XS f32 -> VS2 f16 row-parity pairs). task=(cq<11, mc<19) ----
    if (tid < 209) {
        int cq = tid % 11, mc = tid / 11;
        float4 xv[7];
#pragma unroll
        for (int s = 0; s < 7; ++s) {
            int r = 2 * mc + s; r = r < 42 ? r : 41;   // clamped row feeds only skipped m
            xv[s] = *(const float4*)(smem + XS + r * XSS + 4 * cq);
        }
        f2 tap2[6];
#pragma unroll
        for (int s = 0; s < 6; ++s) { tap2[s].x = fkU[2*s+1]; tap2[s].y = fkU[2*s]; }
#pragma unroll
        for (int k2 = 0; k2 < 2; ++k2) {
            int m = 2 * mc + k2;
            if (m < 37) {
                f2 acc[4];
#pragma unroll
                for (int c = 0; c < 4; ++c) { acc[c].x = 0.f; acc[c].y = 0.f; }
#pragma unroll
                for (int s = 0; s < 6; ++s) {
                    float4 xr = xv[k2 + s];
                    acc[0] += tap2[s] * xr.x;
                    acc[1] += tap2[s] * xr.y;
                    acc[2] += tap2[s] * xr.z;
                    acc[3] += tap2[s] * xr.w;
                }
                unsigned* vp = smemu + VS2 + m * VSS2 + 4 * cq;
                *(uint4*)vp = make_uint4(pkrtz_u(acc[0].x, acc[0].y),
                                         pkrtz_u(acc[1].x, acc[1].y),
                                         pkrtz_u(acc[2].x, acc[2].y),
                                         pkrtz_u(acc[3].x, acc[3].y));
            }
        }
    }
    __syncthreads();

    // ---- B: horizontal up + lrelu (VS2 f16 -> ZS f16), packed f16 FMA ----
    // task=(m<37, chunk q<5): z rows 2m,2m+1, cols 16q..16q+15.
    if (tid < 185) {
        int q = tid % 5, m = tid / 5;
        const unsigned* vb = smemu + VS2 + m * VSS2 + 8 * q;
        uint4 r0 = *(const uint4*)(vb);
        uint4 r1 = *(const uint4*)(vb + 4);
        uint4 r2 = *(const uint4*)(vb + 8);
        uint2 r3 = *(const uint2*)(vb + 12);
        h2 vc[14] = { u2h(r0.x), u2h(r0.y), u2h(r0.z), u2h(r0.w),
                      u2h(r1.x), u2h(r1.y), u2h(r1.z), u2h(r1.w),
                      u2h(r2.x), u2h(r2.y), u2h(r2.z), u2h(r2.w),
                      u2h(r3.x), u2h(r3.y) };
        h2 fo[6], fe[6];
#pragma unroll
        for (int s = 0; s < 6; ++s) { fo[s] = h2s(fkU[2*s+1]); fe[s] = h2s(fkU[2*s]); }
        h2 sl = h2s(0.01f);
        unsigned pk0[8], pk1[8];
#pragma unroll
        for (int h = 0; h < 8; ++h) {        // z cols 16q+2h (even), +1 (odd)
            h2 ae = h2s(0.f), ao = h2s(0.f); // lanes: .x=row 2m, .y=row 2m+1
#pragma unroll
            for (int s = 0; s < 6; ++s) {
                ae += vc[h + s] * fo[s];
                ao += vc[h + s] * fe[s];
            }
            ae = __builtin_elementwise_max(ae, ae * sl);
            ao = __builtin_elementwise_max(ao, ao * sl);
            pk0[h] = pack2(ae.x, ao.x);      // row 2m:   (z_even, z_odd)
            pk1[h] = pack2(ae.y, ao.y);      // row 2m+1: (z_even, z_odd)
        }
        unsigned* z0 = smemu + ZS + (2 * m) * ZSS + 8 * q;
        unsigned* z1 = z0 + ZSS;
        *(uint4*)(z0)     = make_uint4(pk0[0], pk0[1], pk0[2], pk0[3]);
        *(uint4*)(z0 + 4) = make_uint4(pk0[4], pk0[5], pk0[6], pk0[7]);
        *(uint4*)(z1)     = make_uint4(pk1[0], pk1[1], pk1[2], pk1[3]);
        *(uint4*)(z1 + 4) = make_uint4(pk1[4], pk1[5], pk1[6], pk1[7]);
    }
    __syncthreads();

    // ---- C: vertical down (ZS f16 -> WS f16), 4 out rows/task ----
    // task=(col-oct p8<10, row-quad hq<8); reads z rows 8hq..8hq+17.
    // out row 4hq+j uses z row 8hq+u with tap t=u-2j.
    if (tid < 80) {
        int p8 = tid % 10, hq = tid / 10;
        h2 fkh[TAPS];
#pragma unroll
        for (int t = 0; t < TAPS; ++t) fkh[t] = h2s(0.5f * fkU[t]);
        h2 acc[4][4];
#pragma unroll
        for (int j = 0; j < 4; ++j)
#pragma unroll
            for (int d = 0; d < 4; ++d) acc[j][d] = h2s(0.f);
        const unsigned* zbase = smemu + ZS + (8 * hq) * ZSS + 4 * p8;
#pragma unroll
        for (int u = 0; u < 18; ++u) {
            uint4 zr = *(const uint4*)(zbase + u * ZSS);
            h2 z0 = u2h(zr.x), z1 = u2h(zr.y), z2 = u2h(zr.z), z3 = u2h(zr.w);
#pragma unroll
            for (int j = 0; j < 4; ++j) {
                int t = u - 2 * j;
                if (t >= 0 && t < TAPS) {
                    h2 tt = fkh[t];
                    acc[j][0] += tt * z0; acc[j][1] += tt * z1;
                    acc[j][2] += tt * z2; acc[j][3] += tt * z3;
                }
            }
        }
        unsigned* wp = smemu + WS + (4 * hq) * WSS + 4 * p8;
#pragma unroll
        for (int j = 0; j < 4; ++j)
            *(uint4*)(wp + j * WSS) = make_uint4(h2du(acc[j][0]), h2du(acc[j][1]),
                                                 h2du(acc[j][2]), h2du(acc[j][3]));
    }
    __syncthreads();

    // ---- D: horizontal down (WS f16 -> global f32) via v_dot2_f32_f16 ----
    // task=(ho=tid>>3, w4=tid&7): 4 outputs; out[v] = sum_d fdot2(ws_dw[4w4+v+d], fk2[d]).
    {
        int ho = tid >> 3, w4 = tid & 7;
        const unsigned* wp = smemu + WS + ho * WSS + 4 * w4;
        uint4 q0 = *(const uint4*)(wp);
        uint4 q1 = *(const uint4*)(wp + 4);
        unsigned q2 = wp[8];
        unsigned dws[9] = { q0.x, q0.y, q0.z, q0.w, q1.x, q1.y, q1.z, q1.w, q2 };
        unsigned fp[6];
#pragma unroll
        for (int d = 0; d < 6; ++d) fp[d] = pkrtz_u(0.5f * fkU[2*d], 0.5f * fkU[2*d+1]);
        float o[4];
#pragma unroll
        for (int v = 0; v < 4; ++v) {
            float acc = 0.f;
#pragma unroll
            for (int d = 0; d < 6; ++d)
                acc = __builtin_amdgcn_fdot2(u2g(dws[v + d]), u2g(fp[d]), acc, false);
            o[v] = acc;
        }
        *(float4*)(out + ((size_t)nc * 128 + (ho0 + ho)) * 128 + wo0 + 4 * w4)
            = make_float4(o[0], o[1], o[2], o[3]);
    }
}

extern "C" void kernel_launch(void* const* d_in, const int* in_sizes, int n_in,
                              void* d_out, int out_size, void* d_ws, size_t ws_size,
                              hipStream_t stream) {
    const float* x = (const float*)d_in[0];
    const float* f = (const float*)d_in[1];
    float* out = (float*)d_out;
    dim3 grid(16, 1024);
    flrelu_fused<<<grid, 256, 0, stream>>>(x, f, out);
}